// Round 15
// baseline (208.080 us; speedup 1.0000x reference)
//
#include <hip/hip_runtime.h>
#include <stdint.h>

#define TWF 0.2f
#define NPTS 16384

typedef __attribute__((ext_vector_type(8))) short short8;
typedef __attribute__((ext_vector_type(4))) float floatx4;

__device__ __forceinline__ short f2bf(float f){
  unsigned u = __float_as_uint(f);
  u += 0x7fff + ((u >> 16) & 1);           // round-to-nearest-even
  return (short)(u >> 16);
}
__device__ __forceinline__ float bf2f(short s){
  return __uint_as_float(((unsigned)(unsigned short)s) << 16);
}
// tanh(x) = 1 - 2/(exp2(2*log2e*x)+1); exact at +/-inf
__device__ __forceinline__ float fast_tanh(float x){
  float e = __builtin_amdgcn_exp2f(x * 2.885390082f);
  float r = __builtin_amdgcn_rcpf(e + 1.f);
  return fmaf(-2.f, r, 1.f);
}
// cos(pi*t) via v_cos (revolutions)
__device__ __forceinline__ float cospi_t(float t){
  return __builtin_amdgcn_cosf(t * 0.5f);
}
// packed f32x2 -> bf16x2 (RTNE in HW); low 16 = lo, high 16 = hi
__device__ __forceinline__ unsigned cvt_pk_bf16(float lo, float hi){
  unsigned r;
  asm("v_cvt_pk_bf16_f32 %0, %1, %2" : "=v"(r) : "v"(lo), "v"(hi));
  return r;
}

// ws layout (bytes):
//   [0, 4M)      : bf16-swizzled W1/W2 (fragment record order)
//   [4M, 8M)     : rec[16][16384] float4 {xn0, xn1, win, pidx-bits}
//                  SEGMENTED: rec[k][chunk*1024 + local], holes between segs
//   [8M, 8M+1K)  : cnt[256] = count of segment (k=s>>4, chunk=s&15)
// No memset needed: every cnt slot is written every launch (no atomics).
#define WS_W      0
#define WS_REC    (4u<<20)
#define WS_CNT    (8u<<20)

// ---------------- phase 0: weight conv + out-zero + list build ----------------
// Blocks [0,256): one (mat,k,ks) 32x256 W panel each — coalesced f32 read ->
//   LDS bf16 (row-major stride 264, col bit5 XOR'd by row-quad bit0 so the
//   8-row column gathers are 2-way/free) -> fragment short8, contiguous store.
// Blocks [256,512): out-zero + ONE (k,chunk) segment's compacted records
//   (slot-deterministic: plain cnt store, private rec segment, no atomics).
__global__ __launch_bounds__(256) void fbpinn_p0(
    const float* __restrict__ W1, const float* __restrict__ W2,
    const float* __restrict__ x,  const float* __restrict__ xmins,
    const float* __restrict__ xmaxs, short* __restrict__ dst,
    int* __restrict__ cnt, floatx4* __restrict__ rec, float* __restrict__ out)
{
  __shared__ short lds_w[32 * 264];   // 16.5 KB (W-conv blocks)
  __shared__ int   s_wrt[16];         // (list blocks)
  const int bid = blockIdx.x, t = threadIdx.x;

  if (bid < 256){
    // ---- W conversion ----
    int mat = bid >> 7, rem = bid & 127, k = rem >> 3, ks = rem & 7;
    const float* W = mat ? W2 : W1;
    const float* srcRow = W + k * 65536 + (ks * 32) * 256;
    int r  = t >> 3;                   // row in [0,32)
    int cb = (t & 7) * 32;             // col chunk base
    int cbs = cb ^ (((r >> 3) & 1) << 5);   // col-XOR swizzle (bit5 by row-quad&1)
    #pragma unroll
    for (int i = 0; i < 4; i++){
      floatx4 f0 = *(const floatx4*)(srcRow + r * 256 + cb + i * 8);
      floatx4 f1 = *(const floatx4*)(srcRow + r * 256 + cb + i * 8 + 4);
      short8 v;
      v[0] = f2bf(f0[0]); v[1] = f2bf(f0[1]); v[2] = f2bf(f0[2]); v[3] = f2bf(f0[3]);
      v[4] = f2bf(f1[0]); v[5] = f2bf(f1[1]); v[6] = f2bf(f1[2]); v[7] = f2bf(f1[3]);
      *(short8*)&lds_w[r * 264 + cbs + i * 8] = v;
    }
    __syncthreads();
    // emit 1024 fragment records: idx -> lane/jt; content = rows q*8+jj, col j
    size_t base = (size_t)mat * 131072 + k * 8192 + ks * 1024;   // short8 units
    #pragma unroll
    for (int rr = 0; rr < 4; rr++){
      int ridx = t + rr * 256;
      int ln = ridx & 63, jt = ridx >> 6;
      int j  = jt * 16 + (ln & 15);
      int q  = ln >> 4;
      int jx = j ^ ((q & 1) << 5);     // matches write-side swizzle
      short8 v;
      #pragma unroll
      for (int jj = 0; jj < 8; jj++)
        v[jj] = lds_w[(q * 8 + jj) * 264 + jx];
      *(short8*)(dst + (base + ridx) * 8) = v;   // contiguous 1KB/wave
    }
    return;
  }

  // ---- list build (+ out-zero) ----
  int L  = bid - 256;                  // [0,256)
  int k  = L & 15, ch = L >> 4;        // segment (k, chunk)
  int cb = ch * 1024;
  int lane = t & 63, wave = t >> 6;
  if (t < 64) out[L * 64 + t] = 0.f;   // fold memset(out): 256 blocks x 64

  float cx  = (xmins[k * 2 + 0] + xmaxs[k * 2 + 0]) * 0.5f;
  float cy  = (xmins[k * 2 + 1] + xmaxs[k * 2 + 1]) * 0.5f;
  float sxi = 1.f / fmaxf((xmaxs[k * 2 + 0] - xmins[k * 2 + 0]) * 0.5f, 1e-9f);
  float syi = 1.f / fmaxf((xmaxs[k * 2 + 1] - xmins[k * 2 + 1]) * 0.5f, 1e-9f);

  float pxr[4], pyr[4], sum[4], wk[4];
  #pragma unroll
  for (int r = 0; r < 4; r++){
    int p = cb + r * 256 + t;
    float2 xy = *(const float2*)&x[p * 2];
    pxr[r] = xy.x; pyr[r] = xy.y; sum[r] = 0.f; wk[r] = 0.f;
  }
  #pragma unroll
  for (int kk = 0; kk < 16; kk++){
    float mnx = xmins[kk * 2 + 0], mny = xmins[kk * 2 + 1];
    float mxx = xmaxs[kk * 2 + 0], mxy = xmaxs[kk * 2 + 1];
    #pragma unroll
    for (int r = 0; r < 4; r++){
      float tlx = fminf(fmaxf((pxr[r] - (mnx - TWF)) * (1.f/(2.f*TWF)), 0.f), 1.f);
      float trx = fminf(fmaxf(((mxx + TWF) - pxr[r]) * (1.f/(2.f*TWF)), 0.f), 1.f);
      float tly = fminf(fmaxf((pyr[r] - (mny - TWF)) * (1.f/(2.f*TWF)), 0.f), 1.f);
      float tr2 = fminf(fmaxf(((mxy + TWF) - pyr[r]) * (1.f/(2.f*TWF)), 0.f), 1.f);
      float wx = 0.25f * (1.f - cospi_t(tlx)) * (1.f - cospi_t(trx));
      float wy = 0.25f * (1.f - cospi_t(tly)) * (1.f - cospi_t(tr2));
      float w  = wx * wy;
      sum[r] += w;
      if (kk == k) wk[r] = w;
    }
  }
  bool act[4]; float wn[4], xa[4], xb[4];
  unsigned long long msk[4]; int wtot[4];
  #pragma unroll
  for (int r = 0; r < 4; r++){
    float inv = 1.f / (sum[r] + 1e-9f);
    act[r] = wk[r] > 0.f;
    wn[r]  = wk[r] * inv;
    xa[r]  = (pxr[r] - cx) * sxi;
    xb[r]  = (pyr[r] - cy) * syi;
    msk[r] = __ballot(act[r]);
    wtot[r] = (int)__popcll(msk[r]);
  }
  if (lane == 0){
    #pragma unroll
    for (int r = 0; r < 4; r++) s_wrt[wave * 4 + r] = wtot[r];
  }
  __syncthreads();
  int wavebase = 0, blocktot = 0;
  #pragma unroll
  for (int w = 0; w < 4; w++){
    int ws_ = s_wrt[w*4+0] + s_wrt[w*4+1] + s_wrt[w*4+2] + s_wrt[w*4+3];
    blocktot += ws_;
    wavebase += (w < wave) ? ws_ : 0;
  }
  if (t == 0) cnt[k * 16 + ch] = blocktot;   // slot write: NO atomic, NO memset
  int rb = 0;
  #pragma unroll
  for (int r = 0; r < 4; r++){
    if (act[r]){
      int pos = wavebase + rb + (int)__popcll(msk[r] & ((1ull << lane) - 1ull));
      int p = cb + r * 256 + t;
      rec[k * NPTS + cb + pos] = (floatx4){xa[r], xb[r], wn[r], __int_as_float(p)};
    }
    rb += s_wrt[wave * 4 + r];
  }
}

// Packed tanh+bf16 writeback for 32-point tiles: acc[rt][ct] holds D[j'][m],
// j' = (wave*4+rt)*16 + quad*4 + r (4 consecutive rows), m = ct*16+col.
__device__ __forceinline__ void store_h_packed(
    short* lds_h, const floatx4 (&acc)[4][2], const floatx4 (&bb)[4],
    int wave, int quad, int col){
  #pragma unroll
  for (int rt = 0; rt < 4; rt++){
    const int j0    = (wave * 4 + rt) * 16 + quad * 4;
    const int cbase = j0 >> 3;
    const int off   = j0 & 7;
    #pragma unroll
    for (int ct = 0; ct < 2; ct++){
      const int m = ct * 16 + col;
      float t0 = fast_tanh(acc[rt][ct][0] + bb[rt][0]);
      float t1 = fast_tanh(acc[rt][ct][1] + bb[rt][1]);
      float t2 = fast_tanh(acc[rt][ct][2] + bb[rt][2]);
      float t3 = fast_tanh(acc[rt][ct][3] + bb[rt][3]);
      uint2 v = make_uint2(cvt_pk_bf16(t0, t1), cvt_pk_bf16(t2, t3));
      *(uint2*)&lds_h[m * 256 + ((cbase ^ (m & 7)) << 3) + off] = v;
    }
  }
}

// ---------------- phase 1: tiled MLP, 32-point tiles, 7 blocks/CU ----------------
// LDS 20.9KB/block -> 7 blocks/CU (28 waves/CU) vs old 4: barrier stalls of one
// block overlap with 6 other resident blocks. Tile map is ARITHMETIC: 8192
// slots = 256 seg x 32 ti; empty slots skipped with a 1-compare continue
// (no scan, no barriers crossed on skip). XCD-chunk: slots [xcd*1024,+1024)
// = 2 k's -> weight panels L2-resident per XCD.
__global__ __launch_bounds__(256, 7) void fbpinn_p1(
    const float* __restrict__ W0, const float* __restrict__ b0,
    const float* __restrict__ b1, const float* __restrict__ b2,
    const float* __restrict__ W3, const float* __restrict__ b3,
    const short* __restrict__ wsw, const int* __restrict__ cnt,
    const floatx4* __restrict__ rec, float* __restrict__ out)
{
  __shared__ short lds_h[32 * 256];   // 16 KB, swizzled bf16 h tile, [m][j]
  __shared__ float s_xn[32 * 2];
  __shared__ float s_win[32];
  __shared__ int   s_pidx[32];
  __shared__ float s_w3[256];
  __shared__ float s_w0[512];
  __shared__ int   s_c[256];

  const int bid  = blockIdx.x, t = threadIdx.x;
  const int lane = t & 63;
  const int wave = t >> 6;
  const int col  = lane & 15;
  const int quad = lane >> 4;

  if (t < 256) s_c[t] = cnt[t];
  __syncthreads();

  const int xcd = bid & 7;
  const int nb  = gridDim.x >> 3;

  for (int s = bid >> 3; s < 1024; s += nb){
    const int slot = xcd * 1024 + s;
    const int seg  = slot >> 5, ti = slot & 31;
    const int c    = s_c[seg];
    if (ti * 32 >= c) continue;                  // empty slot: no barrier touched
    const int k = seg >> 4, ch = seg & 15;
    const int lbase = ti * 32;
    const floatx4* rbase = rec + k * NPTS + ch * 1024;

    __syncthreads();   // prev tile's layer-3 reads done before overwrite

    // ---- stage: one coalesced 16B record per point ----
    s_w3[t] = W3[k * 256 + t];
    s_w0[t] = W0[k * 512 + t];
    s_w0[256 + t] = W0[k * 512 + 256 + t];
    if (t < 32){
      int li = lbase + t;
      bool valid = li < c;
      floatx4 rcd = rbase[valid ? li : 0];
      s_pidx[t] = __float_as_int(rcd[3]);
      s_win[t]  = valid ? rcd[2] : 0.f;
      s_xn[t * 2 + 0] = rcd[0];
      s_xn[t * 2 + 1] = rcd[1];
    }
    __syncthreads();

    // ---- layer 0 (D=2 -> 256): D[j'][m] = W0^T * xn^T ----
    {
      short8 wfr[4], xfr[2];
      #pragma unroll
      for (int rt = 0; rt < 4; rt++){
        int j = (wave * 4 + rt) * 16 + col;
        short8 a;
        #pragma unroll
        for (int i = 0; i < 8; i++) a[i] = 0;
        a[0] = (quad == 0) ? f2bf(s_w0[j])       : (short)0;
        a[1] = (quad == 0) ? f2bf(s_w0[256 + j]) : (short)0;
        wfr[rt] = a;
      }
      #pragma unroll
      for (int ct = 0; ct < 2; ct++){
        int m = ct * 16 + col;
        short8 b;
        #pragma unroll
        for (int i = 0; i < 8; i++) b[i] = 0;
        b[0] = (quad == 0) ? f2bf(s_xn[m * 2 + 0]) : (short)0;
        b[1] = (quad == 0) ? f2bf(s_xn[m * 2 + 1]) : (short)0;
        xfr[ct] = b;
      }
      floatx4 bb[4];
      #pragma unroll
      for (int rt = 0; rt < 4; rt++)
        bb[rt] = *(const floatx4*)&b0[k * 256 + (wave * 4 + rt) * 16 + quad * 4];
      floatx4 acc[4][2];
      #pragma unroll
      for (int a = 0; a < 4; a++)
        #pragma unroll
        for (int b = 0; b < 2; b++)
          acc[a][b] = (floatx4){0.f, 0.f, 0.f, 0.f};
      #pragma unroll
      for (int rt = 0; rt < 4; rt++)
        #pragma unroll
        for (int ct = 0; ct < 2; ct++)
          acc[rt][ct] = __builtin_amdgcn_mfma_f32_16x16x32_bf16(wfr[rt], xfr[ct], acc[rt][ct], 0, 0, 0);
      store_h_packed(lds_h, acc, bb, wave, quad, col);
      __syncthreads();
    }

    // ---- layers 1,2: D[j'][m] = W^T * h^T ----
    #pragma unroll 1
    for (int layer = 0; layer < 2; layer++){
      const short8* wb = (const short8*)(wsw + (size_t)layer * 1048576)
                         + ((size_t)(k * 8) * 16 + wave * 4) * 64 + lane;
      const float*  bp = layer ? b2 : b1;
      floatx4 bb[4];
      #pragma unroll
      for (int rt = 0; rt < 4; rt++)
        bb[rt] = *(const floatx4*)&bp[k * 256 + (wave * 4 + rt) * 16 + quad * 4];
      floatx4 acc[4][2];
      #pragma unroll
      for (int a = 0; a < 4; a++)
        #pragma unroll
        for (int b = 0; b < 2; b++)
          acc[a][b] = (floatx4){0.f, 0.f, 0.f, 0.f};

      short8 wcur[4];
      #pragma unroll
      for (int rt = 0; rt < 4; rt++) wcur[rt] = wb[rt * 64];

      #pragma unroll
      for (int ks = 0; ks < 8; ks++){
        short8 wnxt[4];
        if (ks < 7){
          #pragma unroll
          for (int rt = 0; rt < 4; rt++)
            wnxt[rt] = wb[(ks + 1) * 1024 + rt * 64];   // prefetch next K-step
        }
        short8 hfr[2];
        #pragma unroll
        for (int ct = 0; ct < 2; ct++){
          int m   = ct * 16 + col;
          int pos = (ks * 4 + quad) ^ (m & 7);
          hfr[ct] = *(const short8*)&lds_h[m * 256 + pos * 8];
        }
        #pragma unroll
        for (int rt = 0; rt < 4; rt++)
          #pragma unroll
          for (int ct = 0; ct < 2; ct++)
            acc[rt][ct] = __builtin_amdgcn_mfma_f32_16x16x32_bf16(wcur[rt], hfr[ct], acc[rt][ct], 0, 0, 0);
        if (ks < 7){
          #pragma unroll
          for (int rt = 0; rt < 4; rt++) wcur[rt] = wnxt[rt];
        }
      }
      __syncthreads();   // all reads of h done before overwrite

      store_h_packed(lds_h, acc, bb, wave, quad, col);
      __syncthreads();
    }

    // ---- layer 3 (256 -> 1): 8 threads per point + weighted scatter ----
    {
      int m = t >> 3, q = t & 7;
      float dot = 0.f;
      #pragma unroll
      for (int cc = 0; cc < 4; cc++){
        int ci  = q * 4 + cc;
        int pos = ci ^ (m & 7);
        short8 hv = *(const short8*)&lds_h[m * 256 + pos * 8];
        #pragma unroll
        for (int jj = 0; jj < 8; jj++)
          dot = fmaf(bf2f(hv[jj]), s_w3[ci * 8 + jj], dot);
      }
      dot += __shfl_xor(dot, 1);
      dot += __shfl_xor(dot, 2);
      dot += __shfl_xor(dot, 4);
      if (q == 0 && s_win[m] != 0.f)
        atomicAdd(&out[s_pidx[m]], s_win[m] * (dot + b3[k]));
    }
  }
}

extern "C" void kernel_launch(void* const* d_in, const int* in_sizes, int n_in,
                              void* d_out, int out_size, void* d_ws, size_t ws_size,
                              hipStream_t stream){
  const float* x     = (const float*)d_in[0];
  const float* W0    = (const float*)d_in[1];
  const float* b0    = (const float*)d_in[2];
  const float* W1    = (const float*)d_in[3];
  const float* b1    = (const float*)d_in[4];
  const float* W2    = (const float*)d_in[5];
  const float* b2    = (const float*)d_in[6];
  const float* W3    = (const float*)d_in[7];
  const float* b3    = (const float*)d_in[8];
  const float* xmins = (const float*)d_in[9];
  const float* xmaxs = (const float*)d_in[10];
  float* out = (float*)d_out;

  char* ws = (char*)d_ws;                     // needs ~8.01 MB
  short*   wsw  = (short*)  (ws + WS_W);
  floatx4* rec  = (floatx4*)(ws + WS_REC);
  int*     cnt  = (int*)    (ws + WS_CNT);

  // Two plain dispatches (graph-capture-safe, no memset, no atomics):
  // p0 = LDS-transpose weight conv + out-zero + deterministic list build;
  // p1 = 32-point-tile MFMA MLP at 7 blocks/CU.
  fbpinn_p0<<<512, 256, 0, stream>>>(W1, W2, x, xmins, xmaxs,
                                     wsw, cnt, rec, out);
  fbpinn_p1<<<1792, 256, 0, stream>>>(W0, b0, b1, b2, W3, b3,
                                      wsw, cnt, rec, out);
}

// Round 17
// 183.402 us; speedup vs baseline: 1.1346x; 1.1346x over previous
//
#include <hip/hip_runtime.h>
#include <stdint.h>

#define TWF 0.2f
#define NPTS 16384

typedef __attribute__((ext_vector_type(8))) short short8;
typedef __attribute__((ext_vector_type(4))) float floatx4;

__device__ __forceinline__ short f2bf(float f){
  unsigned u = __float_as_uint(f);
  u += 0x7fff + ((u >> 16) & 1);           // round-to-nearest-even
  return (short)(u >> 16);
}
__device__ __forceinline__ float bf2f(short s){
  return __uint_as_float(((unsigned)(unsigned short)s) << 16);
}
// tanh(x) = 1 - 2/(exp2(2*log2e*x)+1); exact at +/-inf
__device__ __forceinline__ float fast_tanh(float x){
  float e = __builtin_amdgcn_exp2f(x * 2.885390082f);
  float r = __builtin_amdgcn_rcpf(e + 1.f);
  return fmaf(-2.f, r, 1.f);
}
// cos(pi*t) via v_cos (revolutions)
__device__ __forceinline__ float cospi_t(float t){
  return __builtin_amdgcn_cosf(t * 0.5f);
}
// packed f32x2 -> bf16x2 (RTNE in HW); low 16 = lo, high 16 = hi
__device__ __forceinline__ unsigned cvt_pk_bf16(float lo, float hi){
  unsigned r;
  asm("v_cvt_pk_bf16_f32 %0, %1, %2" : "=v"(r) : "v"(lo), "v"(hi));
  return r;
}

// ws layout (bytes):
//   [0, 4M)      : bf16-swizzled W1/W2 (fragment record order)
//   [4M, 8M)     : rec[16][16384] float4 {xn0, xn1, win, pidx-bits}
//                  SEGMENTED: rec[k][chunk*1024 + local], holes between segs
//   [8M, 8M+1K)  : cnt[256] = count of segment (k=s>>4, chunk=s&15)
// No memset needed: every cnt slot is written every launch (no atomics).
#define WS_W      0
#define WS_REC    (4u<<20)
#define WS_CNT    (8u<<20)

// ---------------- phase 0: weight conv + out-zero + list build ----------------
// (unchanged from R15 — measured working; LDS-transpose conv, deterministic
//  per-segment list build, no atomics, no memset)
__global__ __launch_bounds__(256) void fbpinn_p0(
    const float* __restrict__ W1, const float* __restrict__ W2,
    const float* __restrict__ x,  const float* __restrict__ xmins,
    const float* __restrict__ xmaxs, short* __restrict__ dst,
    int* __restrict__ cnt, floatx4* __restrict__ rec, float* __restrict__ out)
{
  __shared__ short lds_w[32 * 264];   // 16.5 KB (W-conv blocks)
  __shared__ int   s_wrt[16];         // (list blocks)
  const int bid = blockIdx.x, t = threadIdx.x;

  if (bid < 256){
    // ---- W conversion ----
    int mat = bid >> 7, rem = bid & 127, k = rem >> 3, ks = rem & 7;
    const float* W = mat ? W2 : W1;
    const float* srcRow = W + k * 65536 + (ks * 32) * 256;
    int r  = t >> 3;                   // row in [0,32)
    int cb = (t & 7) * 32;             // col chunk base
    int cbs = cb ^ (((r >> 3) & 1) << 5);   // col-XOR swizzle (bit5 by row-quad&1)
    #pragma unroll
    for (int i = 0; i < 4; i++){
      floatx4 f0 = *(const floatx4*)(srcRow + r * 256 + cb + i * 8);
      floatx4 f1 = *(const floatx4*)(srcRow + r * 256 + cb + i * 8 + 4);
      short8 v;
      v[0] = f2bf(f0[0]); v[1] = f2bf(f0[1]); v[2] = f2bf(f0[2]); v[3] = f2bf(f0[3]);
      v[4] = f2bf(f1[0]); v[5] = f2bf(f1[1]); v[6] = f2bf(f1[2]); v[7] = f2bf(f1[3]);
      *(short8*)&lds_w[r * 264 + cbs + i * 8] = v;
    }
    __syncthreads();
    size_t base = (size_t)mat * 131072 + k * 8192 + ks * 1024;   // short8 units
    #pragma unroll
    for (int rr = 0; rr < 4; rr++){
      int ridx = t + rr * 256;
      int ln = ridx & 63, jt = ridx >> 6;
      int j  = jt * 16 + (ln & 15);
      int q  = ln >> 4;
      int jx = j ^ ((q & 1) << 5);     // matches write-side swizzle
      short8 v;
      #pragma unroll
      for (int jj = 0; jj < 8; jj++)
        v[jj] = lds_w[(q * 8 + jj) * 264 + jx];
      *(short8*)(dst + (base + ridx) * 8) = v;   // contiguous 1KB/wave
    }
    return;
  }

  // ---- list build (+ out-zero) ----
  int L  = bid - 256;                  // [0,256)
  int k  = L & 15, ch = L >> 4;        // segment (k, chunk)
  int cb = ch * 1024;
  int lane = t & 63, wave = t >> 6;
  if (t < 64) out[L * 64 + t] = 0.f;   // fold memset(out): 256 blocks x 64

  float cx  = (xmins[k * 2 + 0] + xmaxs[k * 2 + 0]) * 0.5f;
  float cy  = (xmins[k * 2 + 1] + xmaxs[k * 2 + 1]) * 0.5f;
  float sxi = 1.f / fmaxf((xmaxs[k * 2 + 0] - xmins[k * 2 + 0]) * 0.5f, 1e-9f);
  float syi = 1.f / fmaxf((xmaxs[k * 2 + 1] - xmins[k * 2 + 1]) * 0.5f, 1e-9f);

  float pxr[4], pyr[4], sum[4], wk[4];
  #pragma unroll
  for (int r = 0; r < 4; r++){
    int p = cb + r * 256 + t;
    float2 xy = *(const float2*)&x[p * 2];
    pxr[r] = xy.x; pyr[r] = xy.y; sum[r] = 0.f; wk[r] = 0.f;
  }
  #pragma unroll
  for (int kk = 0; kk < 16; kk++){
    float mnx = xmins[kk * 2 + 0], mny = xmins[kk * 2 + 1];
    float mxx = xmaxs[kk * 2 + 0], mxy = xmaxs[kk * 2 + 1];
    #pragma unroll
    for (int r = 0; r < 4; r++){
      float tlx = fminf(fmaxf((pxr[r] - (mnx - TWF)) * (1.f/(2.f*TWF)), 0.f), 1.f);
      float trx = fminf(fmaxf(((mxx + TWF) - pxr[r]) * (1.f/(2.f*TWF)), 0.f), 1.f);
      float tly = fminf(fmaxf((pyr[r] - (mny - TWF)) * (1.f/(2.f*TWF)), 0.f), 1.f);
      float tr2 = fminf(fmaxf(((mxy + TWF) - pyr[r]) * (1.f/(2.f*TWF)), 0.f), 1.f);
      float wx = 0.25f * (1.f - cospi_t(tlx)) * (1.f - cospi_t(trx));
      float wy = 0.25f * (1.f - cospi_t(tly)) * (1.f - cospi_t(tr2));
      float w  = wx * wy;
      sum[r] += w;
      if (kk == k) wk[r] = w;
    }
  }
  bool act[4]; float wn[4], xa[4], xb[4];
  unsigned long long msk[4]; int wtot[4];
  #pragma unroll
  for (int r = 0; r < 4; r++){
    float inv = 1.f / (sum[r] + 1e-9f);
    act[r] = wk[r] > 0.f;
    wn[r]  = wk[r] * inv;
    xa[r]  = (pxr[r] - cx) * sxi;
    xb[r]  = (pyr[r] - cy) * syi;
    msk[r] = __ballot(act[r]);
    wtot[r] = (int)__popcll(msk[r]);
  }
  if (lane == 0){
    #pragma unroll
    for (int r = 0; r < 4; r++) s_wrt[wave * 4 + r] = wtot[r];
  }
  __syncthreads();
  int wavebase = 0, blocktot = 0;
  #pragma unroll
  for (int w = 0; w < 4; w++){
    int ws_ = s_wrt[w*4+0] + s_wrt[w*4+1] + s_wrt[w*4+2] + s_wrt[w*4+3];
    blocktot += ws_;
    wavebase += (w < wave) ? ws_ : 0;
  }
  if (t == 0) cnt[k * 16 + ch] = blocktot;   // slot write: NO atomic, NO memset
  int rb = 0;
  #pragma unroll
  for (int r = 0; r < 4; r++){
    if (act[r]){
      int pos = wavebase + rb + (int)__popcll(msk[r] & ((1ull << lane) - 1ull));
      int p = cb + r * 256 + t;
      rec[k * NPTS + cb + pos] = (floatx4){xa[r], xb[r], wn[r], __int_as_float(p)};
    }
    rb += s_wrt[wave * 4 + r];
  }
}

// Packed tanh+bf16 writeback for 128-point tiles: acc[rt][ct] holds D[j'][m],
// j' = (wave*4+rt)*16 + quad*4 + r (4 consecutive rows), m = ct*16+col in [0,128).
__device__ __forceinline__ void store_h_packed(
    short* lds_h, const floatx4 (&acc)[4][8], const floatx4 (&bb)[4],
    int wave, int quad, int col){
  #pragma unroll
  for (int rt = 0; rt < 4; rt++){
    const int j0    = (wave * 4 + rt) * 16 + quad * 4;
    const int cbase = j0 >> 3;
    const int off   = j0 & 7;
    #pragma unroll
    for (int ct = 0; ct < 8; ct++){
      const int m = ct * 16 + col;
      float t0 = fast_tanh(acc[rt][ct][0] + bb[rt][0]);
      float t1 = fast_tanh(acc[rt][ct][1] + bb[rt][1]);
      float t2 = fast_tanh(acc[rt][ct][2] + bb[rt][2]);
      float t3 = fast_tanh(acc[rt][ct][3] + bb[rt][3]);
      uint2 v = make_uint2(cvt_pk_bf16(t0, t1), cvt_pk_bf16(t2, t3));
      *(uint2*)&lds_h[m * 256 + ((cbase ^ (m & 7)) << 3) + off] = v;
    }
  }
}

// ---------------- phase 1: tiled MLP, 128-POINT tiles ----------------
// R15 diagnosis: wall ~= 46ns x n_tiles across 5 kernel variants (grid/
// structure-invariant) == each tile re-reads the full 256KB W1+W2 panel from
// L2; ~5.6 TB/s effective ceiling. ONLY lever: amortize the panel read over
// more points. 128-pt tiles -> 4x less weight traffic than R15, 2x less than
// the 61-68us R1-R8 floor. ~685 tiles. LDS 70KB -> 2 blocks/CU.
// Slot map: 2048 slots = 256 seg x 8 ti (128 pts each), arithmetic, XCD-chunked.
__global__ __launch_bounds__(256, 2) void fbpinn_p1(
    const float* __restrict__ W0, const float* __restrict__ b0,
    const float* __restrict__ b1, const float* __restrict__ b2,
    const float* __restrict__ W3, const float* __restrict__ b3,
    const short* __restrict__ wsw, const int* __restrict__ cnt,
    const floatx4* __restrict__ rec, float* __restrict__ out)
{
  __shared__ short lds_h[128 * 256];  // 64 KB, swizzled bf16 h tile, [m][j]
  __shared__ float s_xn[128 * 2];
  __shared__ float s_win[128];
  __shared__ int   s_pidx[128];
  __shared__ float s_w3[256];
  __shared__ float s_w0[512];
  __shared__ int   s_c[256];

  const int bid  = blockIdx.x, t = threadIdx.x;
  const int lane = t & 63;
  const int wave = t >> 6;
  const int col  = lane & 15;
  const int quad = lane >> 4;

  if (t < 256) s_c[t] = cnt[t];
  __syncthreads();

  const int xcd = bid & 7;
  const int nb  = gridDim.x >> 3;          // 64 blocks per xcd

  for (int s = bid >> 3; s < 256; s += nb){
    const int slot = xcd * 256 + s;        // [0,2048)
    const int seg  = slot >> 3, ti = slot & 7;
    const int c    = s_c[seg];
    if (ti * 128 >= c) continue;           // empty slot: no barrier touched
    const int k = seg >> 4, ch = seg & 15;
    const int lbase = ti * 128;
    const floatx4* rbase = rec + k * NPTS + ch * 1024;

    __syncthreads();   // prev tile's layer-3 reads done before overwrite

    // ---- stage: one coalesced 16B record per point ----
    s_w3[t] = W3[k * 256 + t];
    s_w0[t] = W0[k * 512 + t];
    s_w0[256 + t] = W0[k * 512 + 256 + t];
    if (t < 128){
      int li = lbase + t;
      bool valid = li < c;
      floatx4 rcd = rbase[valid ? li : 0];
      s_pidx[t] = __float_as_int(rcd[3]);
      s_win[t]  = valid ? rcd[2] : 0.f;
      s_xn[t * 2 + 0] = rcd[0];
      s_xn[t * 2 + 1] = rcd[1];
    }
    __syncthreads();

    // ---- layer 0 (D=2 -> 256): D[j'][m] = W0^T * xn^T ----
    {
      short8 wfr[4];
      #pragma unroll
      for (int rt = 0; rt < 4; rt++){
        int j = (wave * 4 + rt) * 16 + col;
        short8 a;
        #pragma unroll
        for (int i = 0; i < 8; i++) a[i] = 0;
        a[0] = (quad == 0) ? f2bf(s_w0[j])       : (short)0;
        a[1] = (quad == 0) ? f2bf(s_w0[256 + j]) : (short)0;
        wfr[rt] = a;
      }
      floatx4 bb[4];
      #pragma unroll
      for (int rt = 0; rt < 4; rt++)
        bb[rt] = *(const floatx4*)&b0[k * 256 + (wave * 4 + rt) * 16 + quad * 4];
      floatx4 acc[4][8];
      #pragma unroll
      for (int a = 0; a < 4; a++)
        #pragma unroll
        for (int b = 0; b < 8; b++)
          acc[a][b] = (floatx4){0.f, 0.f, 0.f, 0.f};
      #pragma unroll
      for (int ct = 0; ct < 8; ct++){
        int m = ct * 16 + col;
        short8 b;
        #pragma unroll
        for (int i = 0; i < 8; i++) b[i] = 0;
        b[0] = (quad == 0) ? f2bf(s_xn[m * 2 + 0]) : (short)0;
        b[1] = (quad == 0) ? f2bf(s_xn[m * 2 + 1]) : (short)0;
        #pragma unroll
        for (int rt = 0; rt < 4; rt++)
          acc[rt][ct] = __builtin_amdgcn_mfma_f32_16x16x32_bf16(wfr[rt], b, acc[rt][ct], 0, 0, 0);
      }
      store_h_packed(lds_h, acc, bb, wave, quad, col);
      __syncthreads();
    }

    // ---- layers 1,2: D[j'][m] = W^T * h^T; full 256KB panel read amortized
    //      over 128 points (was 32/64) ----
    #pragma unroll 1
    for (int layer = 0; layer < 2; layer++){
      const short8* wb = (const short8*)(wsw + (size_t)layer * 1048576)
                         + ((size_t)(k * 8) * 16 + wave * 4) * 64 + lane;
      const float*  bp = layer ? b2 : b1;
      floatx4 bb[4];
      #pragma unroll
      for (int rt = 0; rt < 4; rt++)
        bb[rt] = *(const floatx4*)&bp[k * 256 + (wave * 4 + rt) * 16 + quad * 4];
      floatx4 acc[4][8];
      #pragma unroll
      for (int a = 0; a < 4; a++)
        #pragma unroll
        for (int b = 0; b < 8; b++)
          acc[a][b] = (floatx4){0.f, 0.f, 0.f, 0.f};

      short8 wcur[4];
      #pragma unroll
      for (int rt = 0; rt < 4; rt++) wcur[rt] = wb[rt * 64];

      #pragma unroll 1
      for (int ks = 0; ks < 8; ks++){
        short8 wnxt[4];
        if (ks < 7){
          #pragma unroll
          for (int rt = 0; rt < 4; rt++)
            wnxt[rt] = wb[(ks + 1) * 1024 + rt * 64];   // prefetch next K-step
        }
        #pragma unroll
        for (int ct = 0; ct < 8; ct++){
          int m   = ct * 16 + col;
          int pos = (ks * 4 + quad) ^ (m & 7);
          short8 hfr = *(const short8*)&lds_h[m * 256 + pos * 8];
          #pragma unroll
          for (int rt = 0; rt < 4; rt++)
            acc[rt][ct] = __builtin_amdgcn_mfma_f32_16x16x32_bf16(wcur[rt], hfr, acc[rt][ct], 0, 0, 0);
        }
        if (ks < 7){
          #pragma unroll
          for (int rt = 0; rt < 4; rt++) wcur[rt] = wnxt[rt];
        }
      }
      __syncthreads();   // all reads of h done before overwrite

      store_h_packed(lds_h, acc, bb, wave, quad, col);
      __syncthreads();
    }

    // ---- layer 3 (256 -> 1): 2 threads per point + weighted scatter ----
    {
      int m = t >> 1, q = t & 1;     // m in [0,128)
      float dot = 0.f;
      #pragma unroll
      for (int cc = 0; cc < 16; cc++){
        int ci  = q * 16 + cc;
        int pos = ci ^ (m & 7);
        short8 hv = *(const short8*)&lds_h[m * 256 + pos * 8];
        #pragma unroll
        for (int jj = 0; jj < 8; jj++)
          dot = fmaf(bf2f(hv[jj]), s_w3[ci * 8 + jj], dot);
      }
      dot += __shfl_xor(dot, 1);
      if (q == 0 && s_win[m] != 0.f)
        atomicAdd(&out[s_pidx[m]], s_win[m] * (dot + b3[k]));
    }
  }
}

extern "C" void kernel_launch(void* const* d_in, const int* in_sizes, int n_in,
                              void* d_out, int out_size, void* d_ws, size_t ws_size,
                              hipStream_t stream){
  const float* x     = (const float*)d_in[0];
  const float* W0    = (const float*)d_in[1];
  const float* b0    = (const float*)d_in[2];
  const float* W1    = (const float*)d_in[3];
  const float* b1    = (const float*)d_in[4];
  const float* W2    = (const float*)d_in[5];
  const float* b2    = (const float*)d_in[6];
  const float* W3    = (const float*)d_in[7];
  const float* b3    = (const float*)d_in[8];
  const float* xmins = (const float*)d_in[9];
  const float* xmaxs = (const float*)d_in[10];
  float* out = (float*)d_out;

  char* ws = (char*)d_ws;                     // needs ~8.01 MB
  short*   wsw  = (short*)  (ws + WS_W);
  floatx4* rec  = (floatx4*)(ws + WS_REC);
  int*     cnt  = (int*)    (ws + WS_CNT);

  // Two plain dispatches (graph-capture-safe, no memset, no atomics):
  // p0 = LDS-transpose weight conv + out-zero + deterministic list build;
  // p1 = 128-point-tile MFMA MLP (weight-panel reads amortized 4x vs R15).
  fbpinn_p0<<<512, 256, 0, stream>>>(W1, W2, x, xmins, xmaxs,
                                     wsw, cnt, rec, out);
  fbpinn_p1<<<512, 256, 0, stream>>>(W0, b0, b1, b2, W3, b3,
                                     wsw, cnt, rec, out);
}